// Round 9
// baseline (8599.197 us; speedup 1.0000x reference)
//
#include <hip/hip_runtime.h>

typedef _Float16 half8 __attribute__((ext_vector_type(8)));
typedef float f32x16 __attribute__((ext_vector_type(16)));
typedef unsigned long long u64;

#define SEQ 512
#define HID 1024
#define HB 65536  // elements per h slice / per x time-slice

// ---- LDS layout (bytes) ----
#define WROW 2064  // 2048 B data + 16 B pad -> conflict-free ds_read_b128
#define LDS_WIH 0        // 32 rows x 2064
#define LDS_WHH 66048    // 32 rows x 2064
#define LDS_GA0 132096   // [64][36] f32 gate accumulator (step parity 0)
#define LDS_GA1 141312   // [64][36] f32 gate accumulator (step parity 1)
#define LDS_ARR 150528   // arrive counter
#define LDS_TOTAL 150592

__device__ __forceinline__ float sigf(float x) { return 1.0f / (1.0f + __expf(-x)); }
__device__ __forceinline__ float tanhfast(float x) {
  x = fminf(fmaxf(x, -44.0f), 44.0f);
  float e = __expf(2.0f * x);
  return (e - 1.0f) / (e + 1.0f);
}

// x (f32 [t][b][1024]) -> xh (f16 blocked [t][kc=128][b=64][cc=8]).
__global__ __launch_bounds__(256, 1) void cvt_blk(const float* __restrict__ in,
                                                  _Float16* __restrict__ out, int nItems) {
  int stride = gridDim.x * blockDim.x;
  for (int g = blockIdx.x * blockDim.x + threadIdx.x; g < nItems; g += stride) {
    int t = g >> 13;        // item = ((t*128 + kc)*64 + b)
    int r = g & 8191;
    int kc = r >> 6;
    int b = r & 63;
    const float* sp = in + (((size_t)t * 64 + b) << 10) + kc * 8;
    float4 v0 = *(const float4*)sp;
    float4 v1 = *(const float4*)(sp + 4);
    half8 o;
    o[0] = (_Float16)v0.x; o[1] = (_Float16)v0.y; o[2] = (_Float16)v0.z; o[3] = (_Float16)v0.w;
    o[4] = (_Float16)v1.x; o[5] = (_Float16)v1.y; o[6] = (_Float16)v1.z; o[7] = (_Float16)v1.w;
    ((half8*)out)[g] = o;
  }
}

// Poll 128 u32 flags (64 u64 words, one per lane) until min >= tgt.
__device__ __forceinline__ void pollFlags(const unsigned* f, unsigned tgt, int lane) {
  const u64* fp = (const u64*)f;
  for (;;) {
    u64 v = __hip_atomic_load(fp + lane, __ATOMIC_RELAXED, __HIP_MEMORY_SCOPE_AGENT);
    unsigned a = (unsigned)v, b = (unsigned)(v >> 32);
    unsigned mn = a < b ? a : b;
    if (__all(mn >= tgt)) break;
    __builtin_amdgcn_s_sleep(1);
  }
}

// [32 batch] x [32 gate] x 512 GEMM over blocked A ([kc][b][8]).
// 4 windows of 8 ksteps; A prefetched 3 windows ahead. B: LDS, conflict-free.
__device__ __forceinline__ f32x16 gemm_k4(const _Float16* aPtr, const char* wB, int bsub) {
  f32x16 acc[4];
#pragma unroll
  for (int q = 0; q < 4; ++q)
#pragma unroll
    for (int i = 0; i < 16; ++i) acc[q][i] = 0.0f;

  half8 aw[4][8];
  half8 bw[2][8];
#pragma unroll
  for (int w0 = 0; w0 < 3; ++w0)
#pragma unroll
    for (int u = 0; u < 8; ++u) aw[w0][u] = *(const half8*)(aPtr + (w0 * 8 + u) * 1024);
#pragma unroll
  for (int u = 0; u < 8; ++u) bw[0][u] = *(const half8*)(wB + u * 32 + bsub);

#pragma unroll
  for (int w = 0; w < 4; ++w) {
    if (w + 3 < 4) {
#pragma unroll
      for (int u = 0; u < 8; ++u)
        aw[(w + 3) & 3][u] = *(const half8*)(aPtr + ((w + 3) * 8 + u) * 1024);
    }
    if (w + 1 < 4) {
#pragma unroll
      for (int u = 0; u < 8; ++u)
        bw[(w + 1) & 1][u] = *(const half8*)(wB + ((w + 1) * 8 + u) * 32 + bsub);
    }
#pragma unroll
    for (int u = 0; u < 8; ++u)
      acc[u & 3] = __builtin_amdgcn_mfma_f32_32x32x16_f16(aw[w & 3][u], bw[w & 1][u],
                                                          acc[u & 3], 0, 0, 0);
  }
  return acc[0] + acc[1] + acc[2] + acc[3];
}

// Accumulate MFMA fragment into a shared gate buffer via LDS float atomics.
__device__ __forceinline__ void addGates(float* gbuf, const f32x16& t, int mtile, int lane) {
#pragma unroll
  for (int r = 0; r < 16; ++r) {
    int bl = (r & 3) + ((r >> 2) << 3) + ((lane >> 5) << 2);
    atomicAdd(&gbuf[(mtile * 32 + bl) * 36 + (lane & 31)], t[r]);
  }
}

// Persistent fused 2-layer LSTM. 256 WGs x 512 threads (8 waves).
// Waves 0-3: recurrent GEMM step k (mtile x khalf split, K=512 each).
// Waves 4-7: input GEMM step k+1 (same split) - concurrent, off critical path.
// Partials ds_add into gA[parity]; epilogue (all threads, 1 item each) reads
// gA[k&1], zeros it, h WT-store (blocked layout), drain, publish, y-stores.
__global__ __launch_bounds__(512, 1) void lstm_fused(
    const _Float16* __restrict__ xh,
    const float* __restrict__ Wih0, const float* __restrict__ Whh0, const float* __restrict__ b0,
    const float* __restrict__ Wih1, const float* __restrict__ Whh1, const float* __restrict__ b1,
    _Float16* __restrict__ h0buf, _Float16* __restrict__ h1buf,
    unsigned* __restrict__ flags, float* __restrict__ out) {
  extern __shared__ char smem[];
  unsigned* arrCnt = (unsigned*)(smem + LDS_ARR);

  const int tid = threadIdx.x;
  const int lane = tid & 63;
  const int wave = tid >> 6;
  const int grp = wave >> 2;    // 0 = recurrent, 1 = input
  const int sub = wave & 3;
  const int mtile = sub & 1;    // batch half
  const int khalf = sub >> 1;   // K half
  const int wg = blockIdx.x;
  const int layer = wg >> 7;
  const int lw = wg & 127;
  const int j0 = lw * 8;

  // ---- prologue: stage W slices (fp32 global -> fp16 LDS) ----
  const float* wsrc0 = layer ? Wih1 : Wih0;
  const float* wsrc1 = layer ? Whh1 : Whh0;
  for (int m = 0; m < 2; ++m) {
    const float* src = m ? wsrc1 : wsrc0;
    char* base = smem + (m ? LDS_WHH : LDS_WIH);
    for (int q = tid; q < 4096; q += 512) {
      int r = q >> 7;               // local gate row 0..31
      int kc = (q & 127) << 3;      // k chunk base (elements)
      int grow = ((r >> 3) << 10) + j0 + (r & 7);  // global gate row
      const float* sp = src + (size_t)grow * 1024 + kc;
      half8 v;
#pragma unroll
      for (int j = 0; j < 8; ++j) v[j] = (_Float16)sp[j];
      *(half8*)(base + r * WROW + kc * 2) = v;
    }
  }
  // bias -> registers (thread's gate column j = tid & 7 is fixed)
  const float* bsrc = layer ? b1 : b0;
  const int jmy = tid & 7;
  const float bi_r = bsrc[j0 + jmy];
  const float bf_r = bsrc[1024 + j0 + jmy];
  const float bg_r = bsrc[2048 + j0 + jmy];
  const float bo_r = bsrc[3072 + j0 + jmy];
  float creg = 0.0f;  // cell state for item tid
  float* gA0 = (float*)(smem + LDS_GA0);
  float* gA1 = (float*)(smem + LDS_GA1);
  for (int q = tid; q < 64 * 36; q += 512) { gA0[q] = 0.0f; gA1[q] = 0.0f; }
  if (tid == 0) *arrCnt = 0u;
  __syncthreads();

  // per-wave constant addressing (blocked A layout; khalf K-offset)
  const int arow = mtile * 32 + (lane & 31);
  const int aoffR = khalf * 32768 + ((lane >> 5) << 9) + arow * 8;
  const int brow = lane & 31;
  const int bsub = (lane >> 5) << 4;
  const char* wIH = smem + LDS_WIH + brow * WROW + khalf * 1024;
  const char* wHH = smem + LDS_WHH + brow * WROW + khalf * 1024;
  _Float16* hSelf = layer ? h1buf : h0buf;
  const unsigned* flagsSelf = flags + (layer << 7);
  float* outy = out;
  float* outh = out + 33554432;
  float* outc = out + 33685504;

  // prologue: input waves add step-0 input gates into gA0
  if (grp == 1) {
    if (layer) pollFlags(flags, 1u, lane);  // need h0 slice 1
    const _Float16* aB = layer ? (h0buf + (size_t)1 * HB) : xh;
    f32x16 t = gemm_k4(aB + aoffR, wIH, bsub);
    addGates(gA0, t, mtile, lane);
  }

  for (int k = 0; k < SEQ; ++k) {
    float* gCur = (k & 1) ? gA1 : gA0;
    float* gNxt = (k & 1) ? gA0 : gA1;
    if (grp == 0) {
      // recurrent GEMM step k
      if (k > 0) pollFlags(flagsSelf, (unsigned)k, lane);
      f32x16 t = gemm_k4(hSelf + (size_t)k * HB + aoffR, wHH, bsub);
      addGates(gCur, t, mtile, lane);
    } else {
      // input GEMM step k+1 (concurrent; layer1 gated on layer0 progress)
      if (k + 1 < SEQ) {
        if (layer) pollFlags(flags, (unsigned)(k + 2), lane);
        const _Float16* aB =
            layer ? (h0buf + (size_t)(k + 2) * HB) : (xh + (size_t)(k + 1) * HB);
        f32x16 t = gemm_k4(aB + aoffR, wIH, bsub);
        addGates(gNxt, t, mtile, lane);
      }
    }
    __syncthreads();  // all adds for step k landed in gCur

    // ---- epilogue step k: 512 threads x 1 item; read gCur, zero behind ----
    u64* hw64 = (u64*)(hSelf + (size_t)(k + 1) * HB);
    const bool last = (k == SEQ - 1);
    int b = tid >> 3, j = tid & 7;
    float vi = gCur[b * 36 + j] + bi_r;
    float vf = gCur[b * 36 + 8 + j] + bf_r;
    float vg = gCur[b * 36 + 16 + j] + bg_r;
    float vo = gCur[b * 36 + 24 + j] + bo_r;
    gCur[b * 36 + j] = 0.0f;
    gCur[b * 36 + 8 + j] = 0.0f;
    gCur[b * 36 + 16 + j] = 0.0f;
    gCur[b * 36 + 24 + j] = 0.0f;
    float i_ = sigf(vi), f_ = sigf(vf), g_ = tanhfast(vg), o_ = sigf(vo);
    float hn = o_ * tanhfast(creg);  // faithful: h uses PREVIOUS cell state
    float cn = f_ * creg + i_ * g_;
    creg = cn;
    // blocked h store: WG-owned contiguous 1KB region, full lines
    union { _Float16 h; unsigned short u; } hb; hb.h = (_Float16)hn;
    unsigned lo = (unsigned)hb.u;
    unsigned pr1 = (unsigned)__shfl_xor((int)lo, 1, 64);
    unsigned pk32 = lo | (pr1 << 16);
    u64 pr2 = (u64)(unsigned)__shfl_xor((int)pk32, 2, 64);
    if ((j & 3) == 0) {
      u64 v = (u64)pk32 | (pr2 << 32);
      __hip_atomic_store(hw64 + (lw * 64 + b) * 2 + (j >> 2), v, __ATOMIC_RELAXED,
                         __HIP_MEMORY_SCOPE_AGENT);
    }
    // release: per-wave drain + LDS arrive; 8th wave publishes flag k+1
    asm volatile("s_waitcnt vmcnt(0)" ::: "memory");
    if (lane == 0) {
      unsigned old = atomicAdd(arrCnt, 1u);
      if (old == 8u * (unsigned)k + 7u)
        __hip_atomic_store(&flags[wg], (unsigned)(k + 1), __ATOMIC_RELAXED,
                           __HIP_MEMORY_SCOPE_AGENT);
    }
    // y / final-state stores (off the release path, reference layout)
    int col = j0 + j;
    if (layer)
      __builtin_nontemporal_store(hn, &outy[(size_t)k * HB + b * HID + col]);
    if (last) {
      __builtin_nontemporal_store(hn, &outh[layer * HB + b * HID + col]);
      __builtin_nontemporal_store(cn, &outc[layer * HB + b * HID + col]);
    }
    __syncthreads();  // gCur zeroed & consumed before next-iter adds
  }
}

extern "C" void kernel_launch(void* const* d_in, const int* in_sizes, int n_in,
                              void* d_out, int out_size, void* d_ws, size_t ws_size,
                              hipStream_t stream) {
  const float* x = (const float*)d_in[0];
  const float* Wih0 = (const float*)d_in[1];
  const float* Whh0 = (const float*)d_in[2];
  const float* b0 = (const float*)d_in[3];
  const float* Wih1 = (const float*)d_in[4];
  const float* Whh1 = (const float*)d_in[5];
  const float* b1 = (const float*)d_in[6];
  float* out = (float*)d_out;

  char* ws = (char*)d_ws;
  _Float16* xh = (_Float16*)ws;                    // 512 x 131072 B (blocked)
  _Float16* h0 = (_Float16*)(ws + 67108864);       // 513 slices x 131072 B (blocked)
  _Float16* h1 = (_Float16*)(ws + 134348800);      // 513 slices x 131072 B (blocked)
  unsigned* flags = (unsigned*)(ws + 201588736);   // 256 u32

  hipMemsetAsync(h0, 0, 131072, stream);
  hipMemsetAsync(h1, 0, 131072, stream);
  hipMemsetAsync(flags, 0, 1024, stream);
  cvt_blk<<<4096, 256, 0, stream>>>(x, xh, 512 * 128 * 64);
  lstm_fused<<<256, 512, LDS_TOTAL, stream>>>(xh, Wih0, Whh0, b0, Wih1, Whh1, b1,
                                              h0, h1, flags, out);
}

// Round 10
// 2831.514 us; speedup vs baseline: 3.0370x; 3.0370x over previous
//
#include <hip/hip_runtime.h>

typedef _Float16 half8 __attribute__((ext_vector_type(8)));
typedef float f32x16 __attribute__((ext_vector_type(16)));
typedef unsigned long long u64;

#define SEQ 512
#define HID 1024
#define HB 65536  // elements per h slice / per x time-slice

// ---- LDS layout (bytes) ----
#define WROW 2064  // 2048 B data + 16 B pad -> conflict-free ds_read_b128
#define LDS_WIH 0        // 32 rows x 2064
#define LDS_WHH 66048    // 32 rows x 2064
#define LDS_GX0 132096   // [64][36] f32 (input-gate partials, ping)
#define LDS_GX1 141312   // [64][36] f32 (pong)
#define LDS_GH  150528   // [64][36] f32 (recurrent partials)
#define LDS_ARR 159744   // arrive counter
#define LDS_TOTAL 159808

__device__ __forceinline__ float sigf(float x) { return 1.0f / (1.0f + __expf(-x)); }
__device__ __forceinline__ float tanhfast(float x) {
  x = fminf(fmaxf(x, -44.0f), 44.0f);
  float e = __expf(2.0f * x);
  return (e - 1.0f) / (e + 1.0f);
}

// x (f32 [t][b][1024]) -> xh (f16 blocked [t][kc=128][b=64][cc=8]).
__global__ __launch_bounds__(256, 1) void cvt_blk(const float* __restrict__ in,
                                                  _Float16* __restrict__ out, int nItems) {
  int stride = gridDim.x * blockDim.x;
  for (int g = blockIdx.x * blockDim.x + threadIdx.x; g < nItems; g += stride) {
    int t = g >> 13;        // item = ((t*128 + kc)*64 + b)
    int r = g & 8191;
    int kc = r >> 6;
    int b = r & 63;
    const float* sp = in + (((size_t)t * 64 + b) << 10) + kc * 8;
    float4 v0 = *(const float4*)sp;
    float4 v1 = *(const float4*)(sp + 4);
    half8 o;
    o[0] = (_Float16)v0.x; o[1] = (_Float16)v0.y; o[2] = (_Float16)v0.z; o[3] = (_Float16)v0.w;
    o[4] = (_Float16)v1.x; o[5] = (_Float16)v1.y; o[6] = (_Float16)v1.z; o[7] = (_Float16)v1.w;
    ((half8*)out)[g] = o;
  }
}

// Poll 128 u32 flags (64 u64 words, one per lane) until min >= tgt.
__device__ __forceinline__ void pollFlags(const unsigned* f, unsigned tgt, int lane) {
  const u64* fp = (const u64*)f;
  for (;;) {
    u64 v = __hip_atomic_load(fp + lane, __ATOMIC_RELAXED, __HIP_MEMORY_SCOPE_AGENT);
    unsigned a = (unsigned)v, b = (unsigned)(v >> 32);
    unsigned mn = a < b ? a : b;
    if (__all(mn >= tgt)) break;
    __builtin_amdgcn_s_sleep(1);
  }
}

// One wave's [32 batch] x [32 gate] x K=1024 GEMM over BLOCKED A ([kc][b][8]).
// DEEP-PIPELINED A preload: first 32 loads clustered via
// sched_group_barrier(VMEM_READ,32) -> RA must keep 32 results live (128 VGPR),
// 32 KB in flight per wave instead of the ~4-deep trickle the default
// scheduler produces. Second 32 issue among the MFMAs. B: LDS, conflict-free.
__device__ __forceinline__ f32x16 gemm_k(const _Float16* aPtr, const char* wB, int bsub) {
  f32x16 acc[4];
#pragma unroll
  for (int q = 0; q < 4; ++q)
#pragma unroll
    for (int i = 0; i < 16; ++i) acc[q][i] = 0.0f;

  half8 aw[64];
#pragma unroll
  for (int u = 0; u < 32; ++u) aw[u] = *(const half8*)(aPtr + u * 1024);
  __builtin_amdgcn_sched_group_barrier(0x20 /*VMEM_READ*/, 32, 0);
#pragma unroll
  for (int u = 32; u < 64; ++u) aw[u] = *(const half8*)(aPtr + u * 1024);

  half8 bw[8];
#pragma unroll
  for (int w = 0; w < 8; ++w) {
#pragma unroll
    for (int u = 0; u < 8; ++u)
      bw[u] = *(const half8*)(wB + (w * 8 + u) * 32 + bsub);
#pragma unroll
    for (int u = 0; u < 8; ++u)
      acc[u & 3] = __builtin_amdgcn_mfma_f32_32x32x16_f16(aw[w * 8 + u], bw[u],
                                                          acc[u & 3], 0, 0, 0);
  }
  return acc[0] + acc[1] + acc[2] + acc[3];
}

__device__ __forceinline__ void writeGates(float* gbuf, const f32x16& t, int mtile, int lane) {
#pragma unroll
  for (int r = 0; r < 16; ++r) {
    int bl = (r & 3) + ((r >> 2) << 3) + ((lane >> 5) << 2);
    gbuf[(mtile * 32 + bl) * 36 + (lane & 31)] = t[r];
  }
}

// Persistent fused 2-layer LSTM (R7 structure). WGs 0..127 layer0, 128..255 layer1.
// Waves 0,1 = input GEMM (phase A, step k+1); waves 2,3 = recurrent (step k).
// h slices in blocked layout [kc][b][8]: WG w fully owns block kc=w&127 ->
// full-line write-through stores, coalesced A reads.
__global__ __launch_bounds__(256, 1) void lstm_fused(
    const _Float16* __restrict__ xh,
    const float* __restrict__ Wih0, const float* __restrict__ Whh0, const float* __restrict__ b0,
    const float* __restrict__ Wih1, const float* __restrict__ Whh1, const float* __restrict__ b1,
    _Float16* __restrict__ h0buf, _Float16* __restrict__ h1buf,
    unsigned* __restrict__ flags, float* __restrict__ out) {
  extern __shared__ char smem[];
  float* gH = (float*)(smem + LDS_GH);
  unsigned* arrCnt = (unsigned*)(smem + LDS_ARR);

  const int tid = threadIdx.x;
  const int lane = tid & 63;
  const int wave = tid >> 6;
  const int mtile = wave & 1;   // which 32 batches
  const int gsel = wave >> 1;   // 0 = input waves, 1 = recurrent waves
  const int wg = blockIdx.x;
  const int layer = wg >> 7;
  const int lw = wg & 127;
  const int j0 = lw * 8;

  // ---- prologue: stage W slices (fp32 global -> fp16 LDS) ----
  const float* wsrc0 = layer ? Wih1 : Wih0;
  const float* wsrc1 = layer ? Whh1 : Whh0;
  for (int m = 0; m < 2; ++m) {
    const float* src = m ? wsrc1 : wsrc0;
    char* base = smem + (m ? LDS_WHH : LDS_WIH);
    for (int q = tid; q < 4096; q += 256) {
      int r = q >> 7;               // local gate row 0..31
      int kc = (q & 127) << 3;      // k chunk base (elements)
      int grow = ((r >> 3) << 10) + j0 + (r & 7);  // global gate row
      const float* sp = src + (size_t)grow * 1024 + kc;
      half8 v;
#pragma unroll
      for (int j = 0; j < 8; ++j) v[j] = (_Float16)sp[j];
      *(half8*)(base + r * WROW + kc * 2) = v;
    }
  }
  // bias -> registers (thread's gate column j = tid & 7 is fixed)
  const float* bsrc = layer ? b1 : b0;
  const int jmy = tid & 7;
  const float bi_r = bsrc[j0 + jmy];
  const float bf_r = bsrc[1024 + j0 + jmy];
  const float bg_r = bsrc[2048 + j0 + jmy];
  const float bo_r = bsrc[3072 + j0 + jmy];
  float creg[2] = {0.0f, 0.0f};  // cell state for items tid, tid+256
  if (tid == 0) *arrCnt = 0u;
  __syncthreads();

  // per-wave constant addressing (blocked A layout)
  const int arow = mtile * 32 + (lane & 31);          // batch row
  const int aoff = ((lane >> 5) << 9) + arow * 8;     // k-half sub-block + batch
  const int brow = lane & 31;                          // gate row for B fragment
  const int bsub = (lane >> 5) << 4;                   // k sub-offset (bytes)
  const char* wIH = smem + LDS_WIH + brow * WROW;
  const char* wHH = smem + LDS_WHH + brow * WROW;
  _Float16* hSelf = layer ? h1buf : h0buf;
  const unsigned* flagsSelf = flags + (layer << 7);
  float* outy = out;
  float* outh = out + 33554432;
  float* outc = out + 33685504;

  // prologue phase A(0): input gates for step 0 -> gX0
  if (gsel == 0) {
    if (layer) pollFlags(flags, 1u, lane);  // need h0 slice 1 (= y0 of t=0)
    const _Float16* aB = layer ? (h0buf + (size_t)1 * HB) : xh;
    f32x16 t = gemm_k(aB + aoff, wIH, bsub);
    writeGates((float*)(smem + LDS_GX0), t, mtile, lane);
  }

  for (int k = 0; k < SEQ; ++k) {
    __syncthreads();  // epilogue k-1 fully done before gH/gX overwrite
    if (gsel == 0) {
      if (k + 1 < SEQ) {  // phase A(k+1)
        if (layer) pollFlags(flags, (unsigned)(k + 2), lane);
        const _Float16* aB =
            layer ? (h0buf + (size_t)(k + 2) * HB) : (xh + (size_t)(k + 1) * HB);
        f32x16 t = gemm_k(aB + aoff, wIH, bsub);
        writeGates((float*)(smem + ((k + 1) & 1 ? LDS_GX1 : LDS_GX0)), t, mtile, lane);
      }
    } else {
      if (k > 0) pollFlags(flagsSelf, (unsigned)k, lane);  // own h slice k ready
      f32x16 t = gemm_k(hSelf + (size_t)k * HB + aoff, wHH, bsub);
      writeGates(gH, t, mtile, lane);
    }
    __syncthreads();  // gX[k&1] (prev iter / prologue) + gH complete

    // ---- epilogue step k (all 256 threads, 2 items each) ----
    const float* gX = (const float*)(smem + ((k & 1) ? LDS_GX1 : LDS_GX0));
    u64* hw64 = (u64*)(hSelf + (size_t)(k + 1) * HB);
    const bool last = (k == SEQ - 1);
    float hnv[2], cnv[2];
#pragma unroll
    for (int it = 0; it < 2; ++it) {
      int item = tid + it * 256;
      int b = item >> 3, j = item & 7;
      float vi = gX[b * 36 + j] + gH[b * 36 + j] + bi_r;
      float vf = gX[b * 36 + 8 + j] + gH[b * 36 + 8 + j] + bf_r;
      float vg = gX[b * 36 + 16 + j] + gH[b * 36 + 16 + j] + bg_r;
      float vo = gX[b * 36 + 24 + j] + gH[b * 36 + 24 + j] + bo_r;
      float i_ = sigf(vi), f_ = sigf(vf), g_ = tanhfast(vg), o_ = sigf(vo);
      float cp = creg[it];
      float hn = o_ * tanhfast(cp);  // faithful: h uses PREVIOUS cell state
      float cn = f_ * cp + i_ * g_;
      creg[it] = cn;
      hnv[it] = hn; cnv[it] = cn;
      // blocked h store: WG-owned contiguous 1KB region, full lines
      union { _Float16 h; unsigned short u; } hb; hb.h = (_Float16)hn;
      unsigned lo = (unsigned)hb.u;
      unsigned pr1 = (unsigned)__shfl_xor((int)lo, 1, 64);
      unsigned pk32 = lo | (pr1 << 16);
      u64 pr2 = (u64)(unsigned)__shfl_xor((int)pk32, 2, 64);
      if ((j & 3) == 0) {
        u64 v = (u64)pk32 | (pr2 << 32);
        __hip_atomic_store(hw64 + (lw * 64 + b) * 2 + (j >> 2), v, __ATOMIC_RELAXED,
                           __HIP_MEMORY_SCOPE_AGENT);
      }
    }
    // release: per-wave drain + LDS arrive; last wave publishes flag k+1
    asm volatile("s_waitcnt vmcnt(0)" ::: "memory");
    if (lane == 0) {
      unsigned old = atomicAdd(arrCnt, 1u);
      if (old == 4u * (unsigned)k + 3u)
        __hip_atomic_store(&flags[wg], (unsigned)(k + 1), __ATOMIC_RELAXED,
                           __HIP_MEMORY_SCOPE_AGENT);
    }
    // y / final-state stores (off the release path, reference layout)
#pragma unroll
    for (int it = 0; it < 2; ++it) {
      int item = tid + it * 256;
      int b = item >> 3, j = item & 7;
      int col = j0 + j;
      if (layer)
        __builtin_nontemporal_store(hnv[it], &outy[(size_t)k * HB + b * HID + col]);
      if (last) {
        __builtin_nontemporal_store(hnv[it], &outh[layer * HB + b * HID + col]);
        __builtin_nontemporal_store(cnv[it], &outc[layer * HB + b * HID + col]);
      }
    }
  }
}

extern "C" void kernel_launch(void* const* d_in, const int* in_sizes, int n_in,
                              void* d_out, int out_size, void* d_ws, size_t ws_size,
                              hipStream_t stream) {
  const float* x = (const float*)d_in[0];
  const float* Wih0 = (const float*)d_in[1];
  const float* Whh0 = (const float*)d_in[2];
  const float* b0 = (const float*)d_in[3];
  const float* Wih1 = (const float*)d_in[4];
  const float* Whh1 = (const float*)d_in[5];
  const float* b1 = (const float*)d_in[6];
  float* out = (float*)d_out;

  char* ws = (char*)d_ws;
  _Float16* xh = (_Float16*)ws;                    // 512 x 131072 B (blocked)
  _Float16* h0 = (_Float16*)(ws + 67108864);       // 513 slices x 131072 B (blocked)
  _Float16* h1 = (_Float16*)(ws + 134348800);      // 513 slices x 131072 B (blocked)
  unsigned* flags = (unsigned*)(ws + 201588736);   // 256 u32

  hipMemsetAsync(h0, 0, 131072, stream);
  hipMemsetAsync(h1, 0, 131072, stream);
  hipMemsetAsync(flags, 0, 1024, stream);
  cvt_blk<<<4096, 256, 0, stream>>>(x, xh, 512 * 128 * 64);
  lstm_fused<<<256, 256, LDS_TOTAL, stream>>>(xh, Wih0, Whh0, b0, Wih1, Whh1, b1,
                                              h0, h1, flags, out);
}